// Round 6
// baseline (333.885 us; speedup 1.0000x reference)
//
#include <hip/hip_runtime.h>
#include <cstdint>

#define DEVFN __device__ __forceinline__

using hh8 = __attribute__((ext_vector_type(8))) _Float16; // 8 fp16 (4 VGPR)
using f4  = __attribute__((ext_vector_type(4))) float;    // MFMA acc

constexpr float RAD  = 0.1125f;          // 1.5*6*0.025/2
constexpr float R2C  = RAD * RAD;
constexpr float EPSF = 1e-12f;
constexpr float FOPI = 1.27323954473516268615f; // 4/pi

DEVFN float sgnf(float a){ return (a > 0.f) ? 1.f : ((a < 0.f) ? -1.f : 0.f); }

DEVFN unsigned short f2h(float f){             // f32 -> fp16 (RNE via v_cvt)
  _Float16 h = (_Float16)f;
  union { _Float16 h; unsigned short u; } x; x.h = h; return x.u;
}
DEVFN hh8 ld_hh8(const unsigned short* p){ return *(const hh8*)p; }
DEVFN hh8 ld_b64x2(const unsigned short* p){   // two ds_read_b64 (8B-aligned rows)
  union { unsigned long long q[2]; hh8 v; } u;
  u.q[0] = *(const unsigned long long*)(p);
  u.q[1] = *(const unsigned long long*)(p + 4);
  return u.v;
}

// Geometry for one neighbor offset (pj - pq). 8 (bin, weight) pairs; weight
// includes poly6 window * factor.  (verified in rounds 1-5)
DEVFN void nbr_geom(float ddx, float ddy, float ddz, float factor, int* bins, float* w8)
{
  float x = ddx / RAD, y = ddy / RAD, z = ddz / RAD;
  float sq = x*x + y*y + z*z;
  float omr = 1.f - sq;
  float win = (omr > 0.f) ? omr*omr*omr : 0.f;
  win *= factor;
  float nrm   = sqrtf(sq);
  float xy_sq = x*x + y*y;
  bool  polar = (1.25f*z*z) > xy_sq;
  float s = polar ? sqrtf(3.f*nrm/(nrm + fabsf(z) + EPSF))
                  : (nrm / sqrtf(xy_sq + EPSF));
  float xc = x*s, yc = y*s;
  float zc = polar ? (sgnf(z)*nrm) : (1.5f*z);
  if (sq < EPSF){ xc = 0.f; yc = 0.f; zc = 0.f; }
  float rxy  = sqrtf(xc*xc + yc*yc);
  bool  xbig = fabsf(xc) >= fabsf(yc);
  float sx = (fabsf(xc) > EPSF) ? xc : 1.f;
  float sy = (fabsf(yc) > EPSF) ? yc : 1.f;
  float u1 = sgnf(xc)*rxy;
  float v1 = u1 * FOPI * atanf(yc / sx);
  float v2 = sgnf(yc)*rxy;
  float u2 = v2 * FOPI * atanf(xc / sy);
  float u = xbig ? u1 : u2;
  float v = xbig ? v1 : v2;
  if (rxy < EPSF){ u = 0.f; v = 0.f; }
  float gx = (u *0.5f + 0.5f)*3.f;
  float gy = (v *0.5f + 0.5f)*3.f;
  float gz = (zc*0.5f + 0.5f)*3.f;
  float fx = fminf(fmaxf(floorf(gx), 0.f), 2.f);
  float fy = fminf(fmaxf(floorf(gy), 0.f), 2.f);
  float fz = fminf(fmaxf(floorf(gz), 0.f), 2.f);
  int ix = (int)fx, iy = (int)fy, iz = (int)fz;
  float tx = gx - fx, ty = gy - fy, tz = gz - fz;
  float wx[2] = {1.f - tx, tx};
  float wy[2] = {1.f - ty, ty};
  float wz[2] = {1.f - tz, tz};
  #pragma unroll
  for (int dz2 = 0; dz2 < 2; ++dz2)
    #pragma unroll
    for (int dy2 = 0; dy2 < 2; ++dy2)
      #pragma unroll
      for (int dx2 = 0; dx2 < 2; ++dx2){
        int c = (dz2 << 2) | (dy2 << 1) | dx2;
        bins[c] = ((iz + dz2)*4 + (iy + dy2))*4 + (ix + dx2);
        w8[c]   = wx[dx2]*wy[dy2]*wz[dz2]*win;
      }
}

// ---------------------------------------------------------------------------
// k_conv0: conv0_fluid + conv0_obstacle + dense0 + concat + relu -> inp1[N][96]
// (fp16 output).  One 256-thread WG per query.
// ---------------------------------------------------------------------------
__global__ __launch_bounds__(256)
void k_conv0(const float* __restrict__ pos, const float* __restrict__ vel,
             const float* __restrict__ box, const float* __restrict__ boxf,
             const float* __restrict__ Wfilt, const float* __restrict__ bcf,
             const float* __restrict__ Ofilt, const float* __restrict__ bco,
             const float* __restrict__ Wd0, const float* __restrict__ bd0,
             const int* __restrict__ nfi, const int* __restrict__ nbi,
             int KB, unsigned short* __restrict__ inp1)
{
  const int n = blockIdx.x, t = threadIdx.x;
  const int lane = t & 63, w = t >> 6, r = lane & 15, h = lane >> 4;

  __shared__ __align__(16) unsigned short LWf[64*64];  // [b][k ^ ((b&7)<<3)]
  __shared__ __align__(16) unsigned short LWo[64*32];  // [b][k ^ ((b&3)<<3)]
  __shared__ __align__(16) unsigned short LBf[16*64];  // [c][k ^ ((c&7)<<3)], rows>=4 zero
  __shared__ __align__(16) unsigned short LBo[16*32];  // [c][k ^ ((c&3)<<3)], rows>=3 zero
  __shared__ float Af[64*4];
  __shared__ float Ao[64*3];
  __shared__ int gjf[64]; __shared__ int gjo[32];
  __shared__ float red[256];

  const float qx = pos[3*n], qy = pos[3*n+1], qz = pos[3*n+2];
  int bins[8]; float w8[8];

  if (w == 0){                              // fluid geometry (KF=64)
    const int k = lane;
    const int j = nfi[(size_t)n*64 + k];
    const float ddx = pos[3*j] - qx, ddy = pos[3*j+1] - qy, ddz = pos[3*j+2] - qz;
    const float d2 = ddx*ddx + ddy*ddy + ddz*ddz;
    unsigned long long zm = __ballot(j == 0);
    int fz = __ffsll(zm) - 1;
    float factor = (j != 0) ? 1.f : ((k == fz && d2 <= R2C && n != 0) ? 1.f : 0.f);
    nbr_geom(ddx, ddy, ddz, factor, bins, w8);
    gjf[k] = j;
  } else if (w == 1){                       // obstacle geometry (KB=32)
    const int k = lane;
    const bool act = k < KB;
    const int j = act ? nbi[(size_t)n*KB + k] : 1;
    float ddx = 0.f, ddy = 0.f, ddz = 0.f, d2 = 1e30f;
    if (act){
      ddx = box[3*j] - qx; ddy = box[3*j+1] - qy; ddz = box[3*j+2] - qz;
      d2 = ddx*ddx + ddy*ddy + ddz*ddz;
    }
    unsigned long long zm = __ballot(act && j == 0);
    int fz = __ffsll(zm) - 1;
    float factor = (j != 0) ? 1.f : ((k == fz && d2 <= R2C) ? 1.f : 0.f);
    nbr_geom(ddx, ddy, ddz, factor, bins, w8);
    if (act) gjo[k] = j;
  } else {                                  // zero the fp16 LDS tiles
    int4 z4 = make_int4(0,0,0,0);
    for (int i = t-128; i < 512; i += 128) *(int4*)&LWf[i*8] = z4;
    for (int i = t-128; i < 256; i += 128) *(int4*)&LWo[i*8] = z4;
    if (t-128 < 128) *(int4*)&LBf[(t-128)*8] = z4;
    if (t-128 <  64) *(int4*)&LBo[(t-128)*8] = z4;
  }
  __syncthreads();

  if (w == 0){
    #pragma unroll
    for (int q = 0; q < 8; ++q){
      int b = bins[q];
      LWf[b*64 + (lane ^ ((b&7)<<3))] = f2h(w8[q]);
    }
  } else if (w == 1){
    if (lane < KB){
      #pragma unroll
      for (int q = 0; q < 8; ++q){
        int b = bins[q];
        LWo[b*32 + (lane ^ ((b&3)<<3))] = f2h(w8[q]);
      }
    }
  } else if (w == 2){                       // BT fluid features [1, vel]
    const int k = lane; const int j = gjf[k];
    LBf[0*64 + k] = f2h(1.f);
    LBf[1*64 + (k ^ 8)]  = f2h(vel[3*j]);
    LBf[2*64 + (k ^ 16)] = f2h(vel[3*j+1]);
    LBf[3*64 + (k ^ 24)] = f2h(vel[3*j+2]);
  } else {                                  // BT obstacle features (normals)
    if (lane < KB){
      const int k = lane; const int j = gjo[k];
      LBo[0*32 + k]        = f2h(boxf[3*j]);
      LBo[1*32 + (k ^ 8)]  = f2h(boxf[3*j+1]);
      LBo[2*32 + (k ^ 16)] = f2h(boxf[3*j+2]);
    }
  }
  __syncthreads();

  // MFMA: A = W @ Fj.  Wave w owns bins [16w,16w+16).
  f4 aF = {0.f,0.f,0.f,0.f}, aO = {0.f,0.f,0.f,0.f};
  {
    const int b = 16*w + r;
    #pragma unroll
    for (int ks = 0; ks < 2; ++ks){
      hh8 a  = ld_hh8(&LWf[b*64 + (((ks*4+h) ^ (b&7))<<3)]);
      hh8 bb = ld_hh8(&LBf[r*64 + (((ks*4+h) ^ (r&7))<<3)]);
      aF = __builtin_amdgcn_mfma_f32_16x16x32_f16(a, bb, aF, 0,0,0);
    }
    hh8 a2 = ld_hh8(&LWo[b*32 + ((h ^ (b&3))<<3)]);
    hh8 b2 = ld_hh8(&LBo[r*32 + ((h ^ (r&3))<<3)]);
    aO = __builtin_amdgcn_mfma_f32_16x16x32_f16(a2, b2, aO, 0,0,0);
  }
  // D layout: col = lane&15, row = (lane>>4)*4 + reg  [HW-verified]
  #pragma unroll
  for (int rr = 0; rr < 4; ++rr){
    int b2 = 16*w + h*4 + rr;
    if (r < 4) Af[b2*4 + r] = aF[rr];
    if (r < 3) Ao[b2*3 + r] = aO[rr];
  }
  __syncthreads();

  // contraction + dense0 + concat + relu
  const int o = t & 31, g = t >> 5;
  float p1 = 0.f;
  for (int b2 = g*8; b2 < g*8 + 8; ++b2)
    #pragma unroll
    for (int c = 0; c < 4; ++c)
      p1 += Af[b2*4 + c] * Wfilt[(b2*4 + c)*32 + o];
  red[t] = p1;
  __syncthreads();
  float a_cf = 0.f;
  if (t < 32){ for (int g2 = 0; g2 < 8; ++g2) a_cf += red[t + 32*g2]; }
  __syncthreads();
  float p2 = 0.f;
  for (int b2 = g*8; b2 < g*8 + 8; ++b2)
    #pragma unroll
    for (int c = 0; c < 3; ++c)
      p2 += Ao[b2*3 + c] * Ofilt[(b2*3 + c)*32 + o];
  red[t] = p2;
  __syncthreads();
  if (t < 32){
    float a_co = 0.f;
    for (int g2 = 0; g2 < 8; ++g2) a_co += red[t + 32*g2];
    const float vx = vel[3*n], vy = vel[3*n+1], vz = vel[3*n+2];
    const float a_df = Wd0[t] + Wd0[32 + t]*vx + Wd0[64 + t]*vy + Wd0[96 + t]*vz;
    const size_t base = (size_t)n * 96;
    inp1[base +      t] = f2h(fmaxf(a_co + bco[t], 0.f));
    inp1[base + 32 + t] = f2h(fmaxf(a_cf + bcf[t], 0.f));
    inp1[base + 64 + t] = f2h(fmaxf(a_df + bd0[t], 0.f));
  }
}

// ---------------------------------------------------------------------------
// k1_scatter<C>: per query, A[64 bins][C] = W @ Fj via MFMA; append dense-ext
// feat row + zero pad; write fp16 row to Abuf with chunk-XOR swizzle.
// Round-6: BT rows padded to 68 u16 (136B) -> column-writes spread over 8
// banks (no XOR needed); B-frag reads via 2x ds_read_b64.  Coalesced u32
// gather (c-fast); geometry (wave 0) overlapped with gather (waves 1-3).
// ---------------------------------------------------------------------------
template<int C>
__global__ __launch_bounds__(256)
void k1_scatter(const float* __restrict__ pos, const unsigned short* __restrict__ feat,
                const int* __restrict__ nfi, int n0, unsigned short* __restrict__ Abuf)
{
  constexpr int Kpad = 64*C + C + (C == 96 ? 32 : 0);   // 6272 / 4160
  constexpr int CT = C/16;
  constexpr int BTS = 68;                  // BT row stride (u16): 136B, 8B-aligned
  const int nloc = blockIdx.x;
  const int n = n0 + nloc;
  const int t = threadIdx.x;
  const int lane = t & 63, w = t >> 6, r = lane & 15, h = lane >> 4;

  __shared__ __align__(16) unsigned short sh[4096 + C*BTS]; // W | BT ; reused as Aout
  unsigned short* W  = sh;
  unsigned short* BT = sh + 4096;
  __shared__ int gj[64];

  // phase 0: wave 0 loads neighbor ids + positions; waves 1-3 zero W
  int jreg = 0; float qx=0.f,qy=0.f,qz=0.f,px=0.f,py=0.f,pz=0.f;
  if (w == 0){
    jreg = nfi[(size_t)n*64 + lane];
    gj[lane] = jreg;
    qx = pos[3*n]; qy = pos[3*n+1]; qz = pos[3*n+2];
    px = pos[3*jreg]; py = pos[3*jreg+1]; pz = pos[3*jreg+2];
  } else {
    int4 z4 = make_int4(0,0,0,0);
    for (int i = t - 64; i < 512; i += 192) *(int4*)&W[i*8] = z4;
  }
  __syncthreads();

  // phase 1: wave 0 geometry + W scatter;  waves 1-3 gather BT (coalesced
  // u32 loads; plain [c][k] writes into stride-68 rows -> 8-way max)
  if (w == 0){
    const int k = lane;
    const float ddx = px - qx, ddy = py - qy, ddz = pz - qz;
    const float d2 = ddx*ddx + ddy*ddy + ddz*ddz;
    unsigned long long zm = __ballot(jreg == 0);
    int fz = __ffsll(zm) - 1;
    float factor = (jreg != 0) ? 1.f : ((k == fz && d2 <= R2C && n != 0) ? 1.f : 0.f);
    int bins[8]; float w8[8];
    nbr_geom(ddx, ddy, ddz, factor, bins, w8);
    #pragma unroll
    for (int q = 0; q < 8; ++q){
      int b = bins[q];
      W[b*64 + (lane ^ ((b&7)<<3))] = f2h(w8[q]);
    }
  } else {
    const int tt = t - 64;                 // 0..191
    if constexpr (C == 96){
      const int kb = tt / 48;              // 0..3 (hoisted div)
      const int cp = tt - kb*48;           // 0..47
      const int c0 = cp*2;
      unsigned short* b0 = BT + c0*BTS;
      unsigned short* b1 = BT + (c0+1)*BTS;
      #pragma unroll 4
      for (int pass = 0; pass < 16; ++pass){
        const int k = pass*4 + kb;
        const int j = gj[k];
        const uint32_t v = *(const uint32_t*)(feat + (size_t)j*96 + c0);
        b0[k] = (unsigned short)(v & 0xffffu);
        b1[k] = (unsigned short)(v >> 16);
      }
    } else {                               // C == 64
      const int kb = tt >> 5;              // 0..5
      const int cp = tt & 31;              // 0..31
      const int c0 = cp*2;
      unsigned short* b0 = BT + c0*BTS;
      unsigned short* b1 = BT + (c0+1)*BTS;
      #pragma unroll 4
      for (int pass = 0; pass < 11; ++pass){
        const int k = pass*6 + kb;
        if (k < 64){
          const int j = gj[k];
          const uint32_t v = *(const uint32_t*)(feat + (size_t)j*64 + c0);
          b0[k] = (unsigned short)(v & 0xffffu);
          b1[k] = (unsigned short)(v >> 16);
        }
      }
    }
  }
  __syncthreads();

  // phase 2: MFMA — wave w owns bins [16w, 16w+16)
  f4 acc[CT];
  #pragma unroll
  for (int ct = 0; ct < CT; ++ct) acc[ct] = f4{0.f,0.f,0.f,0.f};
  const int b = 16*w + r;
  #pragma unroll
  for (int ks = 0; ks < 2; ++ks){
    hh8 a = ld_hh8(&W[b*64 + (((ks*4+h) ^ (b&7))<<3)]);
    const int kc = (ks*4 + h)*8;           // k-chunk offset within row
    #pragma unroll
    for (int ct = 0; ct < CT; ++ct){
      int c = ct*16 + r;
      hh8 bb = ld_b64x2(&BT[c*BTS + kc]);
      acc[ct] = __builtin_amdgcn_mfma_f32_16x16x32_f16(a, bb, acc[ct], 0,0,0);
    }
  }
  __syncthreads();                         // all frag reads done; reuse sh

  // phase 3: writeback (LDS assemble -> swizzled vectorized global store)
  unsigned short* Aout = sh;               // Kpad fp16 row
  #pragma unroll
  for (int ct = 0; ct < CT; ++ct){
    int c = ct*16 + r;
    #pragma unroll
    for (int rr = 0; rr < 4; ++rr){
      int b2 = 16*w + h*4 + rr;            // D: col=lane&15, row=(lane>>4)*4+reg
      Aout[b2*C + c] = f2h(acc[ct][rr]);
    }
  }
  if (t < C) Aout[64*C + t] = feat[(size_t)n*C + t];         // dense extension
  if constexpr (C == 96){
    if (t >= 96 && t < 128) Aout[6240 + t - 96] = 0;         // zero pad
  }
  __syncthreads();

  const int key = nloc & 7;
  const size_t rowBase = (size_t)nloc * Kpad;
  for (int ch = t; ch < Kpad/8; ch += 256){
    int4 v = *(const int4*)&Aout[ch*8];
    *(int4*)&Abuf[rowBase + (size_t)(ch ^ key)*8] = v;
  }
}

// ---------------------------------------------------------------------------
// k_bpack: BpkT[o][kp] fp16 (o-major, chunk-swizzled by o&7) from f32 F + Wd.
// ---------------------------------------------------------------------------
__global__ __launch_bounds__(256)
void k_bpack(const float* __restrict__ F, const float* __restrict__ Wd,
             int kSplit, int Cd, int Kpad, unsigned short* __restrict__ BpkT)
{
  int idx = blockIdx.x*256 + threadIdx.x;
  int chunks = Kpad/8;
  if (idx >= 64*chunks) return;
  int o = idx / chunks, ch = idx - o*chunks;
  union { int4 v; unsigned short u[8]; } pk;
  #pragma unroll
  for (int e = 0; e < 8; ++e){
    int kp = ch*8 + e;
    float f = 0.f;
    if (kp < kSplit)            f = F[(size_t)kp*64 + o];
    else if (kp < kSplit + Cd)  f = Wd[(size_t)(kp - kSplit)*64 + o];
    pk.u[e] = f2h(f);
  }
  *(int4*)&BpkT[((size_t)o*chunks + (ch ^ (o&7)))*8] = pk.v;
}

// ---------------------------------------------------------------------------
// k2_gemm: partial[seg][n][o] = A[n][k] @ B[k][o] over seg's K-range.
// BM=128, BN=64, BK=64, fp16 MFMA 16x16x32; swizzled layouts.
// ---------------------------------------------------------------------------
__global__ __launch_bounds__(256)
void k2_gemm(const unsigned short* __restrict__ Abuf, const unsigned short* __restrict__ BpkT,
             float* __restrict__ partial, int n0, int CHa, int Kpad, int ktot,
             int sB, int NF)
{
  const int t = threadIdx.x;
  const int lane = t & 63, w = t >> 6, r = lane & 15, h = lane >> 4;
  const int seg = blockIdx.y;
  const int ks0 = seg*sB;
  const int ks1 = (ks0 + sB < ktot) ? (ks0 + sB) : ktot;
  const int rowBase = blockIdx.x * 128;

  __shared__ __align__(16) unsigned short Asub[128*64];
  __shared__ __align__(16) unsigned short Bsub[64*64];

  f4 acc[2][4];
  #pragma unroll
  for (int i = 0; i < 2; ++i)
    #pragma unroll
    for (int j = 0; j < 4; ++j) acc[i][j] = f4{0.f,0.f,0.f,0.f};

  for (int ks = ks0; ks < ks1; ++ks){
    #pragma unroll
    for (int i = 0; i < 4; ++i){           // stage A tile (16KB)
      int lin = i*256 + t;
      int row = lin >> 3, lc = lin & 7;
      int grow = rowBase + row; if (grow >= CHa) grow = CHa - 1;
      int4 v = *(const int4*)&Abuf[(size_t)grow*Kpad + ks*64 + lc*8];
      *(int4*)&Asub[lin*8] = v;
    }
    #pragma unroll
    for (int i = 0; i < 2; ++i){           // stage B tile (8KB)
      int lin = i*256 + t;
      int o = lin >> 3, lc = lin & 7;
      int4 v = *(const int4*)&BpkT[(size_t)o*Kpad + ks*64 + lc*8];
      *(int4*)&Bsub[lin*8] = v;
    }
    __syncthreads();
    #pragma unroll
    for (int kh = 0; kh < 2; ++kh){
      hh8 a0 = ld_hh8(&Asub[(w*32 +      r)*64 + (((kh*4+h) ^ (r&7))<<3)]);
      hh8 a1 = ld_hh8(&Asub[(w*32 + 16 + r)*64 + (((kh*4+h) ^ (r&7))<<3)]);
      #pragma unroll
      for (int nt = 0; nt < 4; ++nt){
        hh8 bb = ld_hh8(&Bsub[(nt*16 + r)*64 + (((kh*4+h) ^ (r&7))<<3)]);
        acc[0][nt] = __builtin_amdgcn_mfma_f32_16x16x32_f16(a0, bb, acc[0][nt], 0,0,0);
        acc[1][nt] = __builtin_amdgcn_mfma_f32_16x16x32_f16(a1, bb, acc[1][nt], 0,0,0);
      }
    }
    __syncthreads();
  }

  #pragma unroll
  for (int mt = 0; mt < 2; ++mt)
    #pragma unroll
    for (int rr = 0; rr < 4; ++rr){
      int m = rowBase + w*32 + mt*16 + h*4 + rr;
      if (m < CHa){
        float* op = partial + ((size_t)seg*NF + n0 + m)*64;
        #pragma unroll
        for (int nt = 0; nt < 4; ++nt)
          op[nt*16 + r] = acc[mt][nt][rr];
      }
    }
}

// ---------------------------------------------------------------------------
// k_epi: v = sum_s partial[s] + bc + bd (+resid);
// outRaw (f32, optional), outRelu (fp16, optional)
// ---------------------------------------------------------------------------
__global__ __launch_bounds__(256)
void k_epi(const float* __restrict__ partial, const float* __restrict__ bc,
           const float* __restrict__ bd, const float* __restrict__ resid,
           float* __restrict__ outRaw, unsigned short* __restrict__ outRelu, int total)
{
  const int i = blockIdx.x*256 + threadIdx.x;
  if (i >= total) return;
  float v = 0.f;
  #pragma unroll
  for (int s = 0; s < 8; ++s) v += partial[(size_t)s*total + i];
  const int o = i & 63;
  v += bc[o] + bd[o];
  if (resid)   v += resid[i];
  if (outRaw)  outRaw[i]  = v;
  if (outRelu) outRelu[i] = f2h(fmaxf(v, 0.f));
}

// ---------------------------------------------------------------------------
extern "C" void kernel_launch(void* const* d_in, const int* in_sizes, int n_in,
                              void* d_out, int out_size, void* d_ws, size_t ws_size,
                              hipStream_t stream)
{
  const float* pos  = (const float*)d_in[0];
  const float* vel  = (const float*)d_in[1];
  const float* box  = (const float*)d_in[2];
  const float* boxf = (const float*)d_in[3];
  const float* Wc0f = (const float*)d_in[4];
  const float* bc0f = (const float*)d_in[5];
  const float* Wc0o = (const float*)d_in[6];
  const float* bc0o = (const float*)d_in[7];
  const float* Wd0  = (const float*)d_in[8];
  const float* bd0  = (const float*)d_in[9];
  const float* Wc1  = (const float*)d_in[10];
  const float* bc1  = (const float*)d_in[11];
  const float* Wd1  = (const float*)d_in[12];
  const float* bd1  = (const float*)d_in[13];
  const float* Wc2  = (const float*)d_in[14];
  const float* bc2  = (const float*)d_in[15];
  const float* Wd2  = (const float*)d_in[16];
  const float* bd2  = (const float*)d_in[17];
  const int* nfi = (const int*)d_in[18];
  const int* nbi = (const int*)d_in[20];
  const int NF = in_sizes[0]/3;
  const int KB = in_sizes[20]/NF;
  float* out = (float*)d_out;

  char* wsb = (char*)d_ws;
  auto alloc = [&](size_t bytes){ char* p = wsb; wsb += (bytes + 255) & ~(size_t)255; return p; };
  unsigned short* inp1 = (unsigned short*)alloc((size_t)NF*96*2);
  float* ans1    = (float*)alloc((size_t)NF*64*4);
  unsigned short* inp2 = (unsigned short*)alloc((size_t)NF*64*2);
  float* partial = (float*)alloc((size_t)8*NF*64*4);
  unsigned short* Bpk1 = (unsigned short*)alloc((size_t)64*6272*2);
  unsigned short* Bpk2 = (unsigned short*)alloc((size_t)64*4160*2);
  unsigned short* Abuf = (unsigned short*)wsb;
  size_t usedB = (size_t)(wsb - (char*)d_ws);
  size_t availUS = (ws_size > usedB) ? (ws_size - usedB)/2 : 0;

  // cap chunk at 4096 rows so Abuf chunks stay Infinity-Cache resident
  auto chunkOf = [&](int Kpad)->int{
    long long c = (long long)(availUS / (size_t)Kpad);
    if (c > 4096) c = 4096;
    if (c >= NF) return NF;
    int ch = (int)c & ~127;
    if (ch < 128) ch = 128;
    return ch;
  };

  // layer 0
  k_conv0<<<NF, 256, 0, stream>>>(pos, vel, box, boxf, Wc0f, bc0f, Wc0o, bc0o,
                                  Wd0, bd0, nfi, nbi, KB, inp1);
  // prepack B (conv filter + dense W, transposed + swizzled, fp16)
  k_bpack<<<(64*784 + 255)/256, 256, 0, stream>>>(Wc1, Wd1, 6144, 96, 6272, Bpk1);
  k_bpack<<<(64*520 + 255)/256, 256, 0, stream>>>(Wc2, Wd2, 4096, 64, 4160, Bpk2);

  // layer 1: conv1 + dense1 (K-extension)
  {
    int CH = chunkOf(6272);
    for (int n0 = 0; n0 < NF; n0 += CH){
      int CHa = (n0 + CH < NF) ? CH : (NF - n0);
      k1_scatter<96><<<CHa, 256, 0, stream>>>(pos, inp1, nfi, n0, Abuf);
      int tiles = (CHa + 127)/128;
      k2_gemm<<<dim3(tiles, 8), 256, 0, stream>>>(Abuf, Bpk1, partial, n0, CHa,
                                                  6272, 98, 13, NF);
    }
    k_epi<<<(NF*64 + 255)/256, 256, 0, stream>>>(partial, bc1, bd1, nullptr,
                                                 ans1, inp2, NF*64);
  }
  // layer 2: conv2 + dense2 + residual
  {
    int CH = chunkOf(4160);
    for (int n0 = 0; n0 < NF; n0 += CH){
      int CHa = (n0 + CH < NF) ? CH : (NF - n0);
      k1_scatter<64><<<CHa, 256, 0, stream>>>(pos, inp2, nfi, n0, Abuf);
      int tiles = (CHa + 127)/128;
      k2_gemm<<<dim3(tiles, 8), 256, 0, stream>>>(Abuf, Bpk2, partial, n0, CHa,
                                                  4160, 65, 9, NF);
    }
    k_epi<<<(NF*64 + 255)/256, 256, 0, stream>>>(partial, bc2, bd2, ans1,
                                                 out, nullptr, NF*64);
  }
}

// Round 7
// 252.897 us; speedup vs baseline: 1.3202x; 1.3202x over previous
//
#include <hip/hip_runtime.h>
#include <cstdint>

#define DEVFN __device__ __forceinline__

using hh8 = __attribute__((ext_vector_type(8))) _Float16; // 8 fp16 (4 VGPR)
using f4  = __attribute__((ext_vector_type(4))) float;    // MFMA acc

constexpr float RAD  = 0.1125f;          // 1.5*6*0.025/2
constexpr float R2C  = RAD * RAD;
constexpr float EPSF = 1e-12f;
constexpr float FOPI = 1.27323954473516268615f; // 4/pi

DEVFN float sgnf(float a){ return (a > 0.f) ? 1.f : ((a < 0.f) ? -1.f : 0.f); }

DEVFN unsigned short f2h(float f){             // f32 -> fp16 (RNE via v_cvt)
  _Float16 h = (_Float16)f;
  union { _Float16 h; unsigned short u; } x; x.h = h; return x.u;
}
DEVFN hh8 ld_hh8(const unsigned short* p){ return *(const hh8*)p; }
DEVFN hh8 ld_b64x2(const unsigned short* p){   // two ds_read_b64 (8B-aligned rows)
  union { unsigned long long q[2]; hh8 v; } u;
  u.q[0] = *(const unsigned long long*)(p);
  u.q[1] = *(const unsigned long long*)(p + 4);
  return u.v;
}

// Geometry for one neighbor offset (pj - pq). 8 (bin, weight) pairs; weight
// includes poly6 window * factor.  (verified in rounds 1-6)
DEVFN void nbr_geom(float ddx, float ddy, float ddz, float factor, int* bins, float* w8)
{
  float x = ddx / RAD, y = ddy / RAD, z = ddz / RAD;
  float sq = x*x + y*y + z*z;
  float omr = 1.f - sq;
  float win = (omr > 0.f) ? omr*omr*omr : 0.f;
  win *= factor;
  float nrm   = sqrtf(sq);
  float xy_sq = x*x + y*y;
  bool  polar = (1.25f*z*z) > xy_sq;
  float s = polar ? sqrtf(3.f*nrm/(nrm + fabsf(z) + EPSF))
                  : (nrm / sqrtf(xy_sq + EPSF));
  float xc = x*s, yc = y*s;
  float zc = polar ? (sgnf(z)*nrm) : (1.5f*z);
  if (sq < EPSF){ xc = 0.f; yc = 0.f; zc = 0.f; }
  float rxy  = sqrtf(xc*xc + yc*yc);
  bool  xbig = fabsf(xc) >= fabsf(yc);
  float sx = (fabsf(xc) > EPSF) ? xc : 1.f;
  float sy = (fabsf(yc) > EPSF) ? yc : 1.f;
  float u1 = sgnf(xc)*rxy;
  float v1 = u1 * FOPI * atanf(yc / sx);
  float v2 = sgnf(yc)*rxy;
  float u2 = v2 * FOPI * atanf(xc / sy);
  float u = xbig ? u1 : u2;
  float v = xbig ? v1 : v2;
  if (rxy < EPSF){ u = 0.f; v = 0.f; }
  float gx = (u *0.5f + 0.5f)*3.f;
  float gy = (v *0.5f + 0.5f)*3.f;
  float gz = (zc*0.5f + 0.5f)*3.f;
  float fx = fminf(fmaxf(floorf(gx), 0.f), 2.f);
  float fy = fminf(fmaxf(floorf(gy), 0.f), 2.f);
  float fz = fminf(fmaxf(floorf(gz), 0.f), 2.f);
  int ix = (int)fx, iy = (int)fy, iz = (int)fz;
  float tx = gx - fx, ty = gy - fy, tz = gz - fz;
  float wx[2] = {1.f - tx, tx};
  float wy[2] = {1.f - ty, ty};
  float wz[2] = {1.f - tz, tz};
  #pragma unroll
  for (int dz2 = 0; dz2 < 2; ++dz2)
    #pragma unroll
    for (int dy2 = 0; dy2 < 2; ++dy2)
      #pragma unroll
      for (int dx2 = 0; dx2 < 2; ++dx2){
        int c = (dz2 << 2) | (dy2 << 1) | dx2;
        bins[c] = ((iz + dz2)*4 + (iy + dy2))*4 + (ix + dx2);
        w8[c]   = wx[dx2]*wy[dy2]*wz[dz2]*win;
      }
}

// ---------------------------------------------------------------------------
// k0_scatter: layer-0 A-row builder.  Per query, MFMA computes Af[64x4]
// (fluid conv accumulator) and Ao[64x3] (obstacle), then writes the fp16 row
// A0[512] = [Af(256) | Ao(192) | 1,vx,vy,vz (448..451) | 1.0 (452, bias row)
// | 0-pad].  Contraction with [Wfilt|Ofilt|Wd0|bias] happens in k2_gemm<6>.
// ---------------------------------------------------------------------------
__global__ __launch_bounds__(256)
void k0_scatter(const float* __restrict__ pos, const float* __restrict__ vel,
                const float* __restrict__ box, const float* __restrict__ boxf,
                const int* __restrict__ nfi, const int* __restrict__ nbi,
                int KB, unsigned short* __restrict__ Abuf)
{
  const int n = blockIdx.x, t = threadIdx.x;
  const int lane = t & 63, w = t >> 6, r = lane & 15, h = lane >> 4;

  __shared__ __align__(16) unsigned short LWf[64*64];  // [b][k ^ ((b&7)<<3)]
  __shared__ __align__(16) unsigned short LWo[64*32];  // [b][k ^ ((b&3)<<3)]
  __shared__ __align__(16) unsigned short LBf[16*64];  // [c][k ^ ((c&7)<<3)], rows>=4 zero
  __shared__ __align__(16) unsigned short LBo[16*32];  // [c][k ^ ((c&3)<<3)], rows>=3 zero
  __shared__ __align__(16) unsigned short Aout[512];
  __shared__ int gjf[64]; __shared__ int gjo[32];

  const float qx = pos[3*n], qy = pos[3*n+1], qz = pos[3*n+2];
  int bins[8]; float w8[8];

  if (w == 0){                              // fluid geometry (KF=64)
    const int k = lane;
    const int j = nfi[(size_t)n*64 + k];
    const float ddx = pos[3*j] - qx, ddy = pos[3*j+1] - qy, ddz = pos[3*j+2] - qz;
    const float d2 = ddx*ddx + ddy*ddy + ddz*ddz;
    unsigned long long zm = __ballot(j == 0);
    int fz = __ffsll(zm) - 1;
    float factor = (j != 0) ? 1.f : ((k == fz && d2 <= R2C && n != 0) ? 1.f : 0.f);
    nbr_geom(ddx, ddy, ddz, factor, bins, w8);
    gjf[k] = j;
  } else if (w == 1){                       // obstacle geometry (KB=32)
    const int k = lane;
    const bool act = k < KB;
    const int j = act ? nbi[(size_t)n*KB + k] : 1;
    float ddx = 0.f, ddy = 0.f, ddz = 0.f, d2 = 1e30f;
    if (act){
      ddx = box[3*j] - qx; ddy = box[3*j+1] - qy; ddz = box[3*j+2] - qz;
      d2 = ddx*ddx + ddy*ddy + ddz*ddz;
    }
    unsigned long long zm = __ballot(act && j == 0);
    int fz = __ffsll(zm) - 1;
    float factor = (j != 0) ? 1.f : ((k == fz && d2 <= R2C) ? 1.f : 0.f);
    nbr_geom(ddx, ddy, ddz, factor, bins, w8);
    if (act) gjo[k] = j;
  } else {                                  // zero the fp16 LDS tiles
    int4 z4 = make_int4(0,0,0,0);
    for (int i = t-128; i < 512; i += 128) *(int4*)&LWf[i*8] = z4;
    for (int i = t-128; i < 256; i += 128) *(int4*)&LWo[i*8] = z4;
    if (t-128 < 128) *(int4*)&LBf[(t-128)*8] = z4;
    if (t-128 <  64) *(int4*)&LBo[(t-128)*8] = z4;
  }
  __syncthreads();

  if (w == 0){
    #pragma unroll
    for (int q = 0; q < 8; ++q){
      int b = bins[q];
      LWf[b*64 + (lane ^ ((b&7)<<3))] = f2h(w8[q]);
    }
  } else if (w == 1){
    if (lane < KB){
      #pragma unroll
      for (int q = 0; q < 8; ++q){
        int b = bins[q];
        LWo[b*32 + (lane ^ ((b&3)<<3))] = f2h(w8[q]);
      }
    }
  } else if (w == 2){                       // BT fluid features [1, vel]
    const int k = lane; const int j = gjf[k];
    LBf[0*64 + k] = f2h(1.f);
    LBf[1*64 + (k ^ 8)]  = f2h(vel[3*j]);
    LBf[2*64 + (k ^ 16)] = f2h(vel[3*j+1]);
    LBf[3*64 + (k ^ 24)] = f2h(vel[3*j+2]);
  } else {                                  // BT obstacle features (normals)
    if (lane < KB){
      const int k = lane; const int j = gjo[k];
      LBo[0*32 + k]        = f2h(boxf[3*j]);
      LBo[1*32 + (k ^ 8)]  = f2h(boxf[3*j+1]);
      LBo[2*32 + (k ^ 16)] = f2h(boxf[3*j+2]);
    }
  }
  __syncthreads();

  // MFMA: A = W @ Fj.  Wave w owns bins [16w,16w+16).
  f4 aF = {0.f,0.f,0.f,0.f}, aO = {0.f,0.f,0.f,0.f};
  {
    const int b = 16*w + r;
    #pragma unroll
    for (int ks = 0; ks < 2; ++ks){
      hh8 a  = ld_hh8(&LWf[b*64 + (((ks*4+h) ^ (b&7))<<3)]);
      hh8 bb = ld_hh8(&LBf[r*64 + (((ks*4+h) ^ (r&7))<<3)]);
      aF = __builtin_amdgcn_mfma_f32_16x16x32_f16(a, bb, aF, 0,0,0);
    }
    hh8 a2 = ld_hh8(&LWo[b*32 + ((h ^ (b&3))<<3)]);
    hh8 b2 = ld_hh8(&LBo[r*32 + ((h ^ (r&3))<<3)]);
    aO = __builtin_amdgcn_mfma_f32_16x16x32_f16(a2, b2, aO, 0,0,0);
  }
  // D layout: col = lane&15, row = (lane>>4)*4 + reg  [HW-verified]
  #pragma unroll
  for (int rr = 0; rr < 4; ++rr){
    int b2 = 16*w + h*4 + rr;
    if (r < 4) Aout[b2*4 + r]       = f2h(aF[rr]);
    if (r < 3) Aout[256 + b2*3 + r] = f2h(aO[rr]);
  }
  if (t == 0){ Aout[448] = f2h(1.f); Aout[452] = f2h(1.f); }
  if (t < 3)   Aout[449 + t] = f2h(vel[3*n + t]);
  if (t < 59)  Aout[453 + t] = 0;
  __syncthreads();

  const int key = n & 7;
  if (t < 64){
    int4 v = *(const int4*)&Aout[t*8];
    *(int4*)&Abuf[(size_t)n*512 + (size_t)(t ^ key)*8] = v;
  }
}

// ---------------------------------------------------------------------------
// k1_scatter<C>: per query, A[64 bins][C] = W @ Fj via MFMA; append dense-ext
// feat row + zero pad; write fp16 row to Abuf with chunk-XOR swizzle.
// BT rows padded to 68 u16 (136B); coalesced u32 gather; geometry overlap.
// ---------------------------------------------------------------------------
template<int C>
__global__ __launch_bounds__(256)
void k1_scatter(const float* __restrict__ pos, const unsigned short* __restrict__ feat,
                const int* __restrict__ nfi, int n0, unsigned short* __restrict__ Abuf)
{
  constexpr int Kpad = 64*C + C + (C == 96 ? 32 : 0);   // 6272 / 4160
  constexpr int CT = C/16;
  constexpr int BTS = 68;                  // BT row stride (u16): 136B, 8B-aligned
  const int nloc = blockIdx.x;
  const int n = n0 + nloc;
  const int t = threadIdx.x;
  const int lane = t & 63, w = t >> 6, r = lane & 15, h = lane >> 4;

  __shared__ __align__(16) unsigned short sh[4096 + C*BTS]; // W | BT ; reused as Aout
  unsigned short* W  = sh;
  unsigned short* BT = sh + 4096;
  __shared__ int gj[64];

  int jreg = 0; float qx=0.f,qy=0.f,qz=0.f,px=0.f,py=0.f,pz=0.f;
  if (w == 0){
    jreg = nfi[(size_t)n*64 + lane];
    gj[lane] = jreg;
    qx = pos[3*n]; qy = pos[3*n+1]; qz = pos[3*n+2];
    px = pos[3*jreg]; py = pos[3*jreg+1]; pz = pos[3*jreg+2];
  } else {
    int4 z4 = make_int4(0,0,0,0);
    for (int i = t - 64; i < 512; i += 192) *(int4*)&W[i*8] = z4;
  }
  __syncthreads();

  if (w == 0){
    const int k = lane;
    const float ddx = px - qx, ddy = py - qy, ddz = pz - qz;
    const float d2 = ddx*ddx + ddy*ddy + ddz*ddz;
    unsigned long long zm = __ballot(jreg == 0);
    int fz = __ffsll(zm) - 1;
    float factor = (jreg != 0) ? 1.f : ((k == fz && d2 <= R2C && n != 0) ? 1.f : 0.f);
    int bins[8]; float w8[8];
    nbr_geom(ddx, ddy, ddz, factor, bins, w8);
    #pragma unroll
    for (int q = 0; q < 8; ++q){
      int b = bins[q];
      W[b*64 + (lane ^ ((b&7)<<3))] = f2h(w8[q]);
    }
  } else {
    const int tt = t - 64;                 // 0..191
    if constexpr (C == 96){
      const int kb = tt / 48;              // 0..3 (hoisted div)
      const int cp = tt - kb*48;           // 0..47
      const int c0 = cp*2;
      unsigned short* b0 = BT + c0*BTS;
      unsigned short* b1 = BT + (c0+1)*BTS;
      #pragma unroll 4
      for (int pass = 0; pass < 16; ++pass){
        const int k = pass*4 + kb;
        const int j = gj[k];
        const uint32_t v = *(const uint32_t*)(feat + (size_t)j*96 + c0);
        b0[k] = (unsigned short)(v & 0xffffu);
        b1[k] = (unsigned short)(v >> 16);
      }
    } else {                               // C == 64
      const int kb = tt >> 5;              // 0..5
      const int cp = tt & 31;              // 0..31
      const int c0 = cp*2;
      unsigned short* b0 = BT + c0*BTS;
      unsigned short* b1 = BT + (c0+1)*BTS;
      #pragma unroll 4
      for (int pass = 0; pass < 11; ++pass){
        const int k = pass*6 + kb;
        if (k < 64){
          const int j = gj[k];
          const uint32_t v = *(const uint32_t*)(feat + (size_t)j*64 + c0);
          b0[k] = (unsigned short)(v & 0xffffu);
          b1[k] = (unsigned short)(v >> 16);
        }
      }
    }
  }
  __syncthreads();

  // MFMA — wave w owns bins [16w, 16w+16)
  f4 acc[CT];
  #pragma unroll
  for (int ct = 0; ct < CT; ++ct) acc[ct] = f4{0.f,0.f,0.f,0.f};
  const int b = 16*w + r;
  #pragma unroll
  for (int ks = 0; ks < 2; ++ks){
    hh8 a = ld_hh8(&W[b*64 + (((ks*4+h) ^ (b&7))<<3)]);
    const int kc = (ks*4 + h)*8;           // k-chunk offset within row
    #pragma unroll
    for (int ct = 0; ct < CT; ++ct){
      int c = ct*16 + r;
      hh8 bb = ld_b64x2(&BT[c*BTS + kc]);
      acc[ct] = __builtin_amdgcn_mfma_f32_16x16x32_f16(a, bb, acc[ct], 0,0,0);
    }
  }
  __syncthreads();                         // all frag reads done; reuse sh

  unsigned short* Aout = sh;               // Kpad fp16 row
  #pragma unroll
  for (int ct = 0; ct < CT; ++ct){
    int c = ct*16 + r;
    #pragma unroll
    for (int rr = 0; rr < 4; ++rr){
      int b2 = 16*w + h*4 + rr;            // D: col=lane&15, row=(lane>>4)*4+reg
      Aout[b2*C + c] = f2h(acc[ct][rr]);
    }
  }
  if (t < C) Aout[64*C + t] = feat[(size_t)n*C + t];         // dense extension
  if constexpr (C == 96){
    if (t >= 96 && t < 128) Aout[6240 + t - 96] = 0;         // zero pad
  }
  __syncthreads();

  const int key = nloc & 7;
  const size_t rowBase = (size_t)nloc * Kpad;
  for (int ch = t; ch < Kpad/8; ch += 256){
    int4 v = *(const int4*)&Aout[ch*8];
    *(int4*)&Abuf[rowBase + (size_t)(ch ^ key)*8] = v;
  }
}

// ---------------------------------------------------------------------------
// k_bpack: BpkT[o][kp] fp16 (o-major, chunk-swizzled by o&7) from f32 F + Wd.
// ---------------------------------------------------------------------------
__global__ __launch_bounds__(256)
void k_bpack(const float* __restrict__ F, const float* __restrict__ Wd,
             int kSplit, int Cd, int Kpad, unsigned short* __restrict__ BpkT)
{
  int idx = blockIdx.x*256 + threadIdx.x;
  int chunks = Kpad/8;
  if (idx >= 64*chunks) return;
  int o = idx / chunks, ch = idx - o*chunks;
  union { int4 v; unsigned short u[8]; } pk;
  #pragma unroll
  for (int e = 0; e < 8; ++e){
    int kp = ch*8 + e;
    float f = 0.f;
    if (kp < kSplit)            f = F[(size_t)kp*64 + o];
    else if (kp < kSplit + Cd)  f = Wd[(size_t)(kp - kSplit)*64 + o];
    pk.u[e] = f2h(f);
  }
  *(int4*)&BpkT[((size_t)o*chunks + (ch ^ (o&7)))*8] = pk.v;
}

// ---------------------------------------------------------------------------
// k_bpack0: layer-0 B matrix [512][96] -> Bpk0[96][512] (o-major, swizzled).
// rows 0-255: Wfilt -> cols 32-63; 256-447: Ofilt -> cols 0-31;
// 448-451: Wd0 -> cols 64-95; 452: [bc0o|bc0f|bd0]; rest zero.
// ---------------------------------------------------------------------------
__global__ __launch_bounds__(256)
void k_bpack0(const float* __restrict__ Wfilt, const float* __restrict__ Ofilt,
              const float* __restrict__ Wd0, const float* __restrict__ bco,
              const float* __restrict__ bcf, const float* __restrict__ bd0,
              unsigned short* __restrict__ Bpk0)
{
  int idx = blockIdx.x*256 + threadIdx.x;
  if (idx >= 96*64) return;
  int o = idx >> 6, ch = idx & 63;
  union { int4 v; unsigned short u[8]; } pk;
  #pragma unroll
  for (int e = 0; e < 8; ++e){
    int kp = ch*8 + e;
    float f = 0.f;
    if (kp < 256){
      if (o >= 32 && o < 64) f = Wfilt[(size_t)kp*32 + (o - 32)];
    } else if (kp < 448){
      if (o < 32)            f = Ofilt[(size_t)(kp - 256)*32 + o];
    } else if (kp < 452){
      if (o >= 64)           f = Wd0[(size_t)(kp - 448)*32 + (o - 64)];
    } else if (kp == 452){
      f = (o < 32) ? bco[o] : (o < 64) ? bcf[o - 32] : bd0[o - 64];
    }
    pk.u[e] = f2h(f);
  }
  *(int4*)&Bpk0[((size_t)o*64 + (ch ^ (o&7)))*8] = pk.v;
}

// ---------------------------------------------------------------------------
// k2_gemm<NT>: partial[seg][n][16*NT] = A[n][k] @ B[k][0..16*NT) over seg's
// K-range.  BM=128, BN=16*NT, BK=64, fp16 MFMA 16x16x32; swizzled layouts.
// ---------------------------------------------------------------------------
template<int NT>
__global__ __launch_bounds__(256)
void k2_gemm(const unsigned short* __restrict__ Abuf, const unsigned short* __restrict__ BpkT,
             float* __restrict__ partial, int n0, int CHa, int Kpad, int ktot,
             int sB, int NF)
{
  const int t = threadIdx.x;
  const int lane = t & 63, w = t >> 6, r = lane & 15, h = lane >> 4;
  const int seg = blockIdx.y;
  const int ks0 = seg*sB;
  const int ks1 = (ks0 + sB < ktot) ? (ks0 + sB) : ktot;
  const int rowBase = blockIdx.x * 128;

  __shared__ __align__(16) unsigned short Asub[128*64];
  __shared__ __align__(16) unsigned short Bsub[16*NT*64];

  f4 acc[2][NT];
  #pragma unroll
  for (int i = 0; i < 2; ++i)
    #pragma unroll
    for (int j = 0; j < NT; ++j) acc[i][j] = f4{0.f,0.f,0.f,0.f};

  for (int ks = ks0; ks < ks1; ++ks){
    #pragma unroll
    for (int i = 0; i < 4; ++i){           // stage A tile (16KB)
      int lin = i*256 + t;
      int row = lin >> 3, lc = lin & 7;
      int grow = rowBase + row; if (grow >= CHa) grow = CHa - 1;
      int4 v = *(const int4*)&Abuf[(size_t)grow*Kpad + ks*64 + lc*8];
      *(int4*)&Asub[lin*8] = v;
    }
    #pragma unroll
    for (int i = 0; i < NT/2; ++i){        // stage B tile (16*NT x 64)
      int lin = i*256 + t;
      int o = lin >> 3, lc = lin & 7;
      int4 v = *(const int4*)&BpkT[(size_t)o*Kpad + ks*64 + lc*8];
      *(int4*)&Bsub[lin*8] = v;
    }
    __syncthreads();
    #pragma unroll
    for (int kh = 0; kh < 2; ++kh){
      hh8 a0 = ld_hh8(&Asub[(w*32 +      r)*64 + (((kh*4+h) ^ (r&7))<<3)]);
      hh8 a1 = ld_hh8(&Asub[(w*32 + 16 + r)*64 + (((kh*4+h) ^ (r&7))<<3)]);
      #pragma unroll
      for (int nt = 0; nt < NT; ++nt){
        hh8 bb = ld_hh8(&Bsub[(nt*16 + r)*64 + (((kh*4+h) ^ (r&7))<<3)]);
        acc[0][nt] = __builtin_amdgcn_mfma_f32_16x16x32_f16(a0, bb, acc[0][nt], 0,0,0);
        acc[1][nt] = __builtin_amdgcn_mfma_f32_16x16x32_f16(a1, bb, acc[1][nt], 0,0,0);
      }
    }
    __syncthreads();
  }

  #pragma unroll
  for (int mt = 0; mt < 2; ++mt)
    #pragma unroll
    for (int rr = 0; rr < 4; ++rr){
      int m = rowBase + w*32 + mt*16 + h*4 + rr;
      if (m < CHa){
        float* op = partial + ((size_t)seg*NF + n0 + m)*(16*NT);
        #pragma unroll
        for (int nt = 0; nt < NT; ++nt)
          op[nt*16 + r] = acc[mt][nt][rr];
      }
    }
}

// ---------------------------------------------------------------------------
// k_epi: v = sum_{s<8} partial[s] + bc + bd (+resid);
// outRaw (f32, optional), outRelu (fp16, optional)
// ---------------------------------------------------------------------------
__global__ __launch_bounds__(256)
void k_epi(const float* __restrict__ partial, const float* __restrict__ bc,
           const float* __restrict__ bd, const float* __restrict__ resid,
           float* __restrict__ outRaw, unsigned short* __restrict__ outRelu, int total)
{
  const int i = blockIdx.x*256 + threadIdx.x;
  if (i >= total) return;
  float v = 0.f;
  #pragma unroll
  for (int s = 0; s < 8; ++s) v += partial[(size_t)s*total + i];
  const int o = i & 63;
  v += bc[o] + bd[o];
  if (resid)   v += resid[i];
  if (outRaw)  outRaw[i]  = v;
  if (outRelu) outRelu[i] = f2h(fmaxf(v, 0.f));
}

// ---------------------------------------------------------------------------
// k_epi0: layer-0 epilogue — sum 4 segs (bias folded into GEMM), relu, fp16.
// ---------------------------------------------------------------------------
__global__ __launch_bounds__(256)
void k_epi0(const float* __restrict__ partial, unsigned short* __restrict__ outRelu,
            int total)
{
  const int i = blockIdx.x*256 + threadIdx.x;
  if (i >= total) return;
  float v = 0.f;
  #pragma unroll
  for (int s = 0; s < 4; ++s) v += partial[(size_t)s*total + i];
  outRelu[i] = f2h(fmaxf(v, 0.f));
}

// ---------------------------------------------------------------------------
extern "C" void kernel_launch(void* const* d_in, const int* in_sizes, int n_in,
                              void* d_out, int out_size, void* d_ws, size_t ws_size,
                              hipStream_t stream)
{
  const float* pos  = (const float*)d_in[0];
  const float* vel  = (const float*)d_in[1];
  const float* box  = (const float*)d_in[2];
  const float* boxf = (const float*)d_in[3];
  const float* Wc0f = (const float*)d_in[4];
  const float* bc0f = (const float*)d_in[5];
  const float* Wc0o = (const float*)d_in[6];
  const float* bc0o = (const float*)d_in[7];
  const float* Wd0  = (const float*)d_in[8];
  const float* bd0  = (const float*)d_in[9];
  const float* Wc1  = (const float*)d_in[10];
  const float* bc1  = (const float*)d_in[11];
  const float* Wd1  = (const float*)d_in[12];
  const float* bd1  = (const float*)d_in[13];
  const float* Wc2  = (const float*)d_in[14];
  const float* bc2  = (const float*)d_in[15];
  const float* Wd2  = (const float*)d_in[16];
  const float* bd2  = (const float*)d_in[17];
  const int* nfi = (const int*)d_in[18];
  const int* nbi = (const int*)d_in[20];
  const int NF = in_sizes[0]/3;
  const int KB = in_sizes[20]/NF;
  float* out = (float*)d_out;

  char* wsb = (char*)d_ws;
  auto alloc = [&](size_t bytes){ char* p = wsb; wsb += (bytes + 255) & ~(size_t)255; return p; };
  unsigned short* inp1 = (unsigned short*)alloc((size_t)NF*96*2);
  float* ans1    = (float*)alloc((size_t)NF*64*4);
  unsigned short* inp2 = (unsigned short*)alloc((size_t)NF*64*2);
  float* partial = (float*)alloc((size_t)8*NF*64*4);   // also holds 4*NF*96 (layer 0)
  unsigned short* Bpk1 = (unsigned short*)alloc((size_t)64*6272*2);
  unsigned short* Bpk2 = (unsigned short*)alloc((size_t)64*4160*2);
  unsigned short* Bpk0 = (unsigned short*)alloc((size_t)96*512*2);
  unsigned short* Abuf = (unsigned short*)wsb;
  size_t usedB = (size_t)(wsb - (char*)d_ws);
  size_t availUS = (ws_size > usedB) ? (ws_size - usedB)/2 : 0;

  auto chunkOf = [&](int Kpad)->int{     // round-5 behavior: CH=NF when it fits
    long long c = (long long)(availUS / (size_t)Kpad);
    if (c >= NF) return NF;
    int ch = (int)c & ~127;
    if (ch < 128) ch = 128;
    return ch;
  };

  // prepack B matrices (fp16, transposed + chunk-swizzled)
  k_bpack0<<<(96*64 + 255)/256, 256, 0, stream>>>(Wc0f, Wc0o, Wd0, bc0o, bc0f, bd0, Bpk0);
  k_bpack<<<(64*784 + 255)/256, 256, 0, stream>>>(Wc1, Wd1, 6144, 96, 6272, Bpk1);
  k_bpack<<<(64*520 + 255)/256, 256, 0, stream>>>(Wc2, Wd2, 4096, 64, 4160, Bpk2);

  // layer 0: conv0_fluid + conv0_obstacle + dense0 (+biases) as scatter+GEMM
  {
    k0_scatter<<<NF, 256, 0, stream>>>(pos, vel, box, boxf, nfi, nbi, KB, Abuf);
    int tiles = (NF + 127)/128;
    k2_gemm<6><<<dim3(tiles, 4), 256, 0, stream>>>(Abuf, Bpk0, partial, 0, NF,
                                                   512, 8, 2, NF);
    k_epi0<<<(NF*96 + 255)/256, 256, 0, stream>>>(partial, inp1, NF*96);
  }
  // layer 1: conv1 + dense1 (K-extension)
  {
    int CH = chunkOf(6272);
    for (int n0 = 0; n0 < NF; n0 += CH){
      int CHa = (n0 + CH < NF) ? CH : (NF - n0);
      k1_scatter<96><<<CHa, 256, 0, stream>>>(pos, inp1, nfi, n0, Abuf);
      int tiles = (CHa + 127)/128;
      k2_gemm<4><<<dim3(tiles, 8), 256, 0, stream>>>(Abuf, Bpk1, partial, n0, CHa,
                                                     6272, 98, 13, NF);
    }
    k_epi<<<(NF*64 + 255)/256, 256, 0, stream>>>(partial, bc1, bd1, nullptr,
                                                 ans1, inp2, NF*64);
  }
  // layer 2: conv2 + dense2 + residual
  {
    int CH = chunkOf(4160);
    for (int n0 = 0; n0 < NF; n0 += CH){
      int CHa = (n0 + CH < NF) ? CH : (NF - n0);
      k1_scatter<64><<<CHa, 256, 0, stream>>>(pos, inp2, nfi, n0, Abuf);
      int tiles = (CHa + 127)/128;
      k2_gemm<4><<<dim3(tiles, 8), 256, 0, stream>>>(Abuf, Bpk2, partial, n0, CHa,
                                                     4160, 65, 9, NF);
    }
    k_epi<<<(NF*64 + 255)/256, 256, 0, stream>>>(partial, bc2, bd2, ans1,
                                                 out, nullptr, NF*64);
  }
}

// Round 9
// 250.818 us; speedup vs baseline: 1.3312x; 1.0083x over previous
//
#include <hip/hip_runtime.h>
#include <cstdint>

#define DEVFN __device__ __forceinline__
#define AS1 __attribute__((address_space(1)))
#define AS3 __attribute__((address_space(3)))

using hh8 = __attribute__((ext_vector_type(8))) _Float16; // 8 fp16 (4 VGPR)
using f4  = __attribute__((ext_vector_type(4))) float;    // MFMA acc

constexpr float RAD  = 0.1125f;          // 1.5*6*0.025/2
constexpr float R2C  = RAD * RAD;
constexpr float EPSF = 1e-12f;
constexpr float FOPI = 1.27323954473516268615f; // 4/pi

DEVFN float sgnf(float a){ return (a > 0.f) ? 1.f : ((a < 0.f) ? -1.f : 0.f); }

DEVFN unsigned short f2h(float f){             // f32 -> fp16 (RNE via v_cvt)
  _Float16 h = (_Float16)f;
  union { _Float16 h; unsigned short u; } x; x.h = h; return x.u;
}
DEVFN hh8 ld_hh8(const unsigned short* p){ return *(const hh8*)p; }
DEVFN hh8 ld_b64x2(const unsigned short* p){   // two ds_read_b64 (8B-aligned rows)
  union { unsigned long long q[2]; hh8 v; } u;
  u.q[0] = *(const unsigned long long*)(p);
  u.q[1] = *(const unsigned long long*)(p + 4);
  return u.v;
}
DEVFN void gld16(const void* g, void* l){      // global -> LDS, 16B per lane
  __builtin_amdgcn_global_load_lds((const AS1 void*)g, (AS3 void*)l, 16, 0, 0);
}

// Geometry for one neighbor offset (pj - pq). 8 (bin, weight) pairs; weight
// includes poly6 window * factor.  (verified in rounds 1-7)
DEVFN void nbr_geom(float ddx, float ddy, float ddz, float factor, int* bins, float* w8)
{
  float x = ddx / RAD, y = ddy / RAD, z = ddz / RAD;
  float sq = x*x + y*y + z*z;
  float omr = 1.f - sq;
  float win = (omr > 0.f) ? omr*omr*omr : 0.f;
  win *= factor;
  float nrm   = sqrtf(sq);
  float xy_sq = x*x + y*y;
  bool  polar = (1.25f*z*z) > xy_sq;
  float s = polar ? sqrtf(3.f*nrm/(nrm + fabsf(z) + EPSF))
                  : (nrm / sqrtf(xy_sq + EPSF));
  float xc = x*s, yc = y*s;
  float zc = polar ? (sgnf(z)*nrm) : (1.5f*z);
  if (sq < EPSF){ xc = 0.f; yc = 0.f; zc = 0.f; }
  float rxy  = sqrtf(xc*xc + yc*yc);
  bool  xbig = fabsf(xc) >= fabsf(yc);
  float sx = (fabsf(xc) > EPSF) ? xc : 1.f;
  float sy = (fabsf(yc) > EPSF) ? yc : 1.f;
  float u1 = sgnf(xc)*rxy;
  float v1 = u1 * FOPI * atanf(yc / sx);
  float v2 = sgnf(yc)*rxy;
  float u2 = v2 * FOPI * atanf(xc / sy);
  float u = xbig ? u1 : u2;
  float v = xbig ? v1 : v2;
  if (rxy < EPSF){ u = 0.f; v = 0.f; }
  float gx = (u *0.5f + 0.5f)*3.f;
  float gy = (v *0.5f + 0.5f)*3.f;
  float gz = (zc*0.5f + 0.5f)*3.f;
  float fx = fminf(fmaxf(floorf(gx), 0.f), 2.f);
  float fy = fminf(fmaxf(floorf(gy), 0.f), 2.f);
  float fz = fminf(fmaxf(floorf(gz), 0.f), 2.f);
  int ix = (int)fx, iy = (int)fy, iz = (int)fz;
  float tx = gx - fx, ty = gy - fy, tz = gz - fz;
  float wx[2] = {1.f - tx, tx};
  float wy[2] = {1.f - ty, ty};
  float wz[2] = {1.f - tz, tz};
  #pragma unroll
  for (int dz2 = 0; dz2 < 2; ++dz2)
    #pragma unroll
    for (int dy2 = 0; dy2 < 2; ++dy2)
      #pragma unroll
      for (int dx2 = 0; dx2 < 2; ++dx2){
        int c = (dz2 << 2) | (dy2 << 1) | dx2;
        bins[c] = ((iz + dz2)*4 + (iy + dy2))*4 + (ix + dx2);
        w8[c]   = wx[dx2]*wy[dy2]*wz[dz2]*win;
      }
}

// ---------------------------------------------------------------------------
// k0_scatter: layer-0 A-row builder (unchanged, passing since round 7).
// ---------------------------------------------------------------------------
__global__ __launch_bounds__(256)
void k0_scatter(const float* __restrict__ pos, const float* __restrict__ vel,
                const float* __restrict__ box, const float* __restrict__ boxf,
                const int* __restrict__ nfi, const int* __restrict__ nbi,
                int KB, unsigned short* __restrict__ Abuf)
{
  const int n = blockIdx.x, t = threadIdx.x;
  const int lane = t & 63, w = t >> 6, r = lane & 15, h = lane >> 4;

  __shared__ __align__(16) unsigned short LWf[64*64];
  __shared__ __align__(16) unsigned short LWo[64*32];
  __shared__ __align__(16) unsigned short LBf[16*64];
  __shared__ __align__(16) unsigned short LBo[16*32];
  __shared__ __align__(16) unsigned short Aout[512];
  __shared__ int gjf[64]; __shared__ int gjo[32];

  const float qx = pos[3*n], qy = pos[3*n+1], qz = pos[3*n+2];
  int bins[8]; float w8[8];

  if (w == 0){
    const int k = lane;
    const int j = nfi[(size_t)n*64 + k];
    const float ddx = pos[3*j] - qx, ddy = pos[3*j+1] - qy, ddz = pos[3*j+2] - qz;
    const float d2 = ddx*ddx + ddy*ddy + ddz*ddz;
    unsigned long long zm = __ballot(j == 0);
    int fz = __ffsll(zm) - 1;
    float factor = (j != 0) ? 1.f : ((k == fz && d2 <= R2C && n != 0) ? 1.f : 0.f);
    nbr_geom(ddx, ddy, ddz, factor, bins, w8);
    gjf[k] = j;
  } else if (w == 1){
    const int k = lane;
    const bool act = k < KB;
    const int j = act ? nbi[(size_t)n*KB + k] : 1;
    float ddx = 0.f, ddy = 0.f, ddz = 0.f, d2 = 1e30f;
    if (act){
      ddx = box[3*j] - qx; ddy = box[3*j+1] - qy; ddz = box[3*j+2] - qz;
      d2 = ddx*ddx + ddy*ddy + ddz*ddz;
    }
    unsigned long long zm = __ballot(act && j == 0);
    int fz = __ffsll(zm) - 1;
    float factor = (j != 0) ? 1.f : ((k == fz && d2 <= R2C) ? 1.f : 0.f);
    nbr_geom(ddx, ddy, ddz, factor, bins, w8);
    if (act) gjo[k] = j;
  } else {
    int4 z4 = make_int4(0,0,0,0);
    for (int i = t-128; i < 512; i += 128) *(int4*)&LWf[i*8] = z4;
    for (int i = t-128; i < 256; i += 128) *(int4*)&LWo[i*8] = z4;
    if (t-128 < 128) *(int4*)&LBf[(t-128)*8] = z4;
    if (t-128 <  64) *(int4*)&LBo[(t-128)*8] = z4;
  }
  __syncthreads();

  if (w == 0){
    #pragma unroll
    for (int q = 0; q < 8; ++q){
      int b = bins[q];
      LWf[b*64 + (lane ^ ((b&7)<<3))] = f2h(w8[q]);
    }
  } else if (w == 1){
    if (lane < KB){
      #pragma unroll
      for (int q = 0; q < 8; ++q){
        int b = bins[q];
        LWo[b*32 + (lane ^ ((b&3)<<3))] = f2h(w8[q]);
      }
    }
  } else if (w == 2){
    const int k = lane; const int j = gjf[k];
    LBf[0*64 + k] = f2h(1.f);
    LBf[1*64 + (k ^ 8)]  = f2h(vel[3*j]);
    LBf[2*64 + (k ^ 16)] = f2h(vel[3*j+1]);
    LBf[3*64 + (k ^ 24)] = f2h(vel[3*j+2]);
  } else {
    if (lane < KB){
      const int k = lane; const int j = gjo[k];
      LBo[0*32 + k]        = f2h(boxf[3*j]);
      LBo[1*32 + (k ^ 8)]  = f2h(boxf[3*j+1]);
      LBo[2*32 + (k ^ 16)] = f2h(boxf[3*j+2]);
    }
  }
  __syncthreads();

  f4 aF = {0.f,0.f,0.f,0.f}, aO = {0.f,0.f,0.f,0.f};
  {
    const int b = 16*w + r;
    #pragma unroll
    for (int ks = 0; ks < 2; ++ks){
      hh8 a  = ld_hh8(&LWf[b*64 + (((ks*4+h) ^ (b&7))<<3)]);
      hh8 bb = ld_hh8(&LBf[r*64 + (((ks*4+h) ^ (r&7))<<3)]);
      aF = __builtin_amdgcn_mfma_f32_16x16x32_f16(a, bb, aF, 0,0,0);
    }
    hh8 a2 = ld_hh8(&LWo[b*32 + ((h ^ (b&3))<<3)]);
    hh8 b2 = ld_hh8(&LBo[r*32 + ((h ^ (r&3))<<3)]);
    aO = __builtin_amdgcn_mfma_f32_16x16x32_f16(a2, b2, aO, 0,0,0);
  }
  #pragma unroll
  for (int rr = 0; rr < 4; ++rr){
    int b2 = 16*w + h*4 + rr;
    if (r < 4) Aout[b2*4 + r]       = f2h(aF[rr]);
    if (r < 3) Aout[256 + b2*3 + r] = f2h(aO[rr]);
  }
  if (t == 0){ Aout[448] = f2h(1.f); Aout[452] = f2h(1.f); }
  if (t < 3)   Aout[449 + t] = f2h(vel[3*n + t]);
  if (t < 59)  Aout[453 + t] = 0;
  __syncthreads();

  const int key = n & 7;
  if (t < 64){
    int4 v = *(const int4*)&Aout[t*8];
    *(int4*)&Abuf[(size_t)n*512 + (size_t)(t ^ key)*8] = v;
  }
}

// ---------------------------------------------------------------------------
// k1_scatter<C>: per query, A[64 bins][C] = W @ Fj via MFMA (operands SWAPPED
// so D is transposed: lane holds 4 consecutive channels of one bin -> phase-3
// is 6 aligned u64 LDS stores).  Bin stride padded (100/68 u16).
// Round-9 fix: pad channels + tail are explicitly ZEROED — uninitialized LDS
// can decode as NaN fp16 and NaN*0 = NaN in the k2 MFMA (round-8 failure).
// ---------------------------------------------------------------------------
template<int C>
__global__ __launch_bounds__(256)
void k1_scatter(const float* __restrict__ pos, const unsigned short* __restrict__ feat,
                const int* __restrict__ nfi, int n0, unsigned short* __restrict__ Abuf)
{
  constexpr int BST  = (C == 96) ? 100 : 68;            // padded bin stride
  constexpr int Kpad = (C == 96) ? 6528 : 4416;         // 64*BST + C (+tail), %64==0
  constexpr int CT = C/16;
  constexpr int BTS = 68;                  // BT row stride (u16): 136B, 8B-aligned
  const int nloc = blockIdx.x;
  const int n = n0 + nloc;
  const int t = threadIdx.x;
  const int lane = t & 63, w = t >> 6, r = lane & 15, h = lane >> 4;

  __shared__ __align__(16) unsigned short sh[4096 + C*BTS]; // W | BT ; reused as Aout
  unsigned short* W  = sh;
  unsigned short* BT = sh + 4096;
  __shared__ int gj[64];

  int jreg = 0; float qx=0.f,qy=0.f,qz=0.f,px=0.f,py=0.f,pz=0.f;
  if (w == 0){
    jreg = nfi[(size_t)n*64 + lane];
    gj[lane] = jreg;
    qx = pos[3*n]; qy = pos[3*n+1]; qz = pos[3*n+2];
    px = pos[3*jreg]; py = pos[3*jreg+1]; pz = pos[3*jreg+2];
  } else {
    int4 z4 = make_int4(0,0,0,0);
    for (int i = t - 64; i < 512; i += 192) *(int4*)&W[i*8] = z4;
  }
  __syncthreads();

  if (w == 0){
    const int k = lane;
    const float ddx = px - qx, ddy = py - qy, ddz = pz - qz;
    const float d2 = ddx*ddx + ddy*ddy + ddz*ddz;
    unsigned long long zm = __ballot(jreg == 0);
    int fz = __ffsll(zm) - 1;
    float factor = (jreg != 0) ? 1.f : ((k == fz && d2 <= R2C && n != 0) ? 1.f : 0.f);
    int bins[8]; float w8[8];
    nbr_geom(ddx, ddy, ddz, factor, bins, w8);
    #pragma unroll
    for (int q = 0; q < 8; ++q){
      int b = bins[q];
      W[b*64 + (lane ^ ((b&7)<<3))] = f2h(w8[q]);
    }
  } else {
    const int tt = t - 64;                 // 0..191
    if constexpr (C == 96){
      const int kb = tt / 48;              // 0..3 (hoisted div)
      const int cp = tt - kb*48;           // 0..47
      const int c0 = cp*2;
      unsigned short* b0 = BT + c0*BTS;
      unsigned short* b1 = BT + (c0+1)*BTS;
      #pragma unroll 4
      for (int pass = 0; pass < 16; ++pass){
        const int k = pass*4 + kb;
        const int j = gj[k];
        const uint32_t v = *(const uint32_t*)(feat + (size_t)j*96 + c0);
        b0[k] = (unsigned short)(v & 0xffffu);
        b1[k] = (unsigned short)(v >> 16);
      }
    } else {                               // C == 64
      const int kb = tt >> 5;              // 0..5
      const int cp = tt & 31;              // 0..31
      const int c0 = cp*2;
      unsigned short* b0 = BT + c0*BTS;
      unsigned short* b1 = BT + (c0+1)*BTS;
      #pragma unroll 4
      for (int pass = 0; pass < 11; ++pass){
        const int k = pass*6 + kb;
        if (k < 64){
          const int j = gj[k];
          const uint32_t v = *(const uint32_t*)(feat + (size_t)j*64 + c0);
          b0[k] = (unsigned short)(v & 0xffffu);
          b1[k] = (unsigned short)(v >> 16);
        }
      }
    }
  }
  __syncthreads();

  // MFMA — operands swapped: acc = (W@Feat)^T tile.
  // Lane: col(lane&15) = bin b = 16w+r;  row((lane>>4)*4+reg) = channel.
  f4 acc[CT];
  #pragma unroll
  for (int ct = 0; ct < CT; ++ct) acc[ct] = f4{0.f,0.f,0.f,0.f};
  const int b = 16*w + r;
  #pragma unroll
  for (int ks = 0; ks < 2; ++ks){
    hh8 a = ld_hh8(&W[b*64 + (((ks*4+h) ^ (b&7))<<3)]);
    const int kc = (ks*4 + h)*8;           // k-chunk offset within row
    #pragma unroll
    for (int ct = 0; ct < CT; ++ct){
      int c = ct*16 + r;
      hh8 bb = ld_b64x2(&BT[c*BTS + kc]);
      acc[ct] = __builtin_amdgcn_mfma_f32_16x16x32_f16(bb, a, acc[ct], 0,0,0);
    }
  }
  __syncthreads();                         // all frag reads done; reuse sh

  // phase 3: transposed-D writeback — 4 consecutive channels per u64 store
  unsigned short* Aout = sh;               // Kpad fp16 row (bins at stride BST)
  #pragma unroll
  for (int ct = 0; ct < CT; ++ct){
    unsigned long long pk =
        (unsigned long long)f2h(acc[ct][0])
      | ((unsigned long long)f2h(acc[ct][1]) << 16)
      | ((unsigned long long)f2h(acc[ct][2]) << 32)
      | ((unsigned long long)f2h(acc[ct][3]) << 48);
    const int c0 = ct*16 + h*4;            // channel base (row of D')
    *(unsigned long long*)&Aout[b*BST + c0] = pk;   // b = 16w+r (col of D')
  }
  // zero the pad channels (4 per bin) — 256 threads cover 64 bins x 4
  Aout[(t >> 2)*BST + C + (t & 3)] = 0;
  if constexpr (C == 96){
    if (t < 32) Aout[6496 + t] = 0;        // tail 64*100+96 .. 6527
  }
  if (t < C) Aout[64*BST + t] = feat[(size_t)n*C + t];       // dense extension
  __syncthreads();

  const int key = nloc & 7;
  const size_t rowBase = (size_t)nloc * Kpad;
  for (int ch = t; ch < Kpad/8; ch += 256){
    int4 v = *(const int4*)&Aout[ch*8];
    *(int4*)&Abuf[rowBase + (size_t)(ch ^ key)*8] = v;
  }
}

// ---------------------------------------------------------------------------
// k_bpack: BpkT[o][kp] fp16 (o-major, chunk-swizzled by o&7) from f32 F + Wd.
// Bin-padded K layout: kp < 64*BST -> bin = kp/BST, c = kp%BST (c>=Cin -> 0);
// [64*BST, +Cd) -> dense Wd; rest 0.
// ---------------------------------------------------------------------------
__global__ __launch_bounds__(256)
void k_bpack(const float* __restrict__ F, const float* __restrict__ Wd,
             int Cin, int BST, int Cd, int Kpad, unsigned short* __restrict__ BpkT)
{
  int idx = blockIdx.x*256 + threadIdx.x;
  int chunks = Kpad/8;
  if (idx >= 64*chunks) return;
  int o = idx / chunks, ch = idx - o*chunks;
  const int kDense = 64*BST;
  union { int4 v; unsigned short u[8]; } pk;
  #pragma unroll
  for (int e = 0; e < 8; ++e){
    int kp = ch*8 + e;
    float f = 0.f;
    if (kp < kDense){
      int bin = kp / BST, c = kp - bin*BST;
      if (c < Cin) f = F[((size_t)bin*Cin + c)*64 + o];
    } else if (kp < kDense + Cd){
      f = Wd[(size_t)(kp - kDense)*64 + o];
    }
    pk.u[e] = f2h(f);
  }
  *(int4*)&BpkT[((size_t)o*chunks + (ch ^ (o&7)))*8] = pk.v;
}

// ---------------------------------------------------------------------------
// k_bpack0: layer-0 B matrix [512][96] -> Bpk0[96][512] (o-major, swizzled).
// ---------------------------------------------------------------------------
__global__ __launch_bounds__(256)
void k_bpack0(const float* __restrict__ Wfilt, const float* __restrict__ Ofilt,
              const float* __restrict__ Wd0, const float* __restrict__ bco,
              const float* __restrict__ bcf, const float* __restrict__ bd0,
              unsigned short* __restrict__ Bpk0)
{
  int idx = blockIdx.x*256 + threadIdx.x;
  if (idx >= 96*64) return;
  int o = idx >> 6, ch = idx & 63;
  union { int4 v; unsigned short u[8]; } pk;
  #pragma unroll
  for (int e = 0; e < 8; ++e){
    int kp = ch*8 + e;
    float f = 0.f;
    if (kp < 256){
      if (o >= 32 && o < 64) f = Wfilt[(size_t)kp*32 + (o - 32)];
    } else if (kp < 448){
      if (o < 32)            f = Ofilt[(size_t)(kp - 256)*32 + o];
    } else if (kp < 452){
      if (o >= 64)           f = Wd0[(size_t)(kp - 448)*32 + (o - 64)];
    } else if (kp == 452){
      f = (o < 32) ? bco[o] : (o < 64) ? bcf[o - 32] : bd0[o - 64];
    }
    pk.u[e] = f2h(f);
  }
  *(int4*)&Bpk0[((size_t)o*64 + (ch ^ (o&7)))*8] = pk.v;
}

// ---------------------------------------------------------------------------
// k2_gemm<NT>: partial[seg][n][16*NT] = A @ B over seg's K-range.
// BM=128, BN=16*NT, BK=64; A/B staged via global_load_lds (16B/lane).
// ---------------------------------------------------------------------------
template<int NT>
__global__ __launch_bounds__(256)
void k2_gemm(const unsigned short* __restrict__ Abuf, const unsigned short* __restrict__ BpkT,
             float* __restrict__ partial, int n0, int CHa, int Kpad, int ktot,
             int sB, int NF)
{
  const int t = threadIdx.x;
  const int lane = t & 63, w = t >> 6, r = lane & 15, h = lane >> 4;
  const int wbase = t & ~63;               // wave-uniform thread base
  const int seg = blockIdx.y;
  const int ks0 = seg*sB;
  const int ks1 = (ks0 + sB < ktot) ? (ks0 + sB) : ktot;
  const int rowBase = blockIdx.x * 128;

  __shared__ __align__(16) unsigned short Asub[128*64];
  __shared__ __align__(16) unsigned short Bsub[16*NT*64];

  f4 acc[2][NT];
  #pragma unroll
  for (int i = 0; i < 2; ++i)
    #pragma unroll
    for (int j = 0; j < NT; ++j) acc[i][j] = f4{0.f,0.f,0.f,0.f};

  for (int ks = ks0; ks < ks1; ++ks){
    #pragma unroll
    for (int i = 0; i < 4; ++i){           // stage A tile (16KB) via gload_lds
      int lin = i*256 + t;
      int row = lin >> 3, lc = lin & 7;
      int grow = rowBase + row; if (grow >= CHa) grow = CHa - 1;
      gld16(&Abuf[(size_t)grow*Kpad + ks*64 + lc*8],
            &Asub[(size_t)(i*256 + wbase)*8]);
    }
    #pragma unroll
    for (int i = 0; i < NT/2; ++i){        // stage B tile via gload_lds
      int lin = i*256 + t;
      int o = lin >> 3, lc = lin & 7;
      gld16(&BpkT[(size_t)o*Kpad + ks*64 + lc*8],
            &Bsub[(size_t)(i*256 + wbase)*8]);
    }
    __syncthreads();
    #pragma unroll
    for (int kh = 0; kh < 2; ++kh){
      hh8 a0 = ld_hh8(&Asub[(w*32 +      r)*64 + (((kh*4+h) ^ (r&7))<<3)]);
      hh8 a1 = ld_hh8(&Asub[(w*32 + 16 + r)*64 + (((kh*4+h) ^ (r&7))<<3)]);
      #pragma unroll
      for (int nt = 0; nt < NT; ++nt){
        hh8 bb = ld_hh8(&Bsub[(nt*16 + r)*64 + (((kh*4+h) ^ (r&7))<<3)]);
        acc[0][nt] = __builtin_amdgcn_mfma_f32_16x16x32_f16(a0, bb, acc[0][nt], 0,0,0);
        acc[1][nt] = __builtin_amdgcn_mfma_f32_16x16x32_f16(a1, bb, acc[1][nt], 0,0,0);
      }
    }
    __syncthreads();
  }

  #pragma unroll
  for (int mt = 0; mt < 2; ++mt)
    #pragma unroll
    for (int rr = 0; rr < 4; ++rr){
      int m = rowBase + w*32 + mt*16 + h*4 + rr;
      if (m < CHa){
        float* op = partial + ((size_t)seg*NF + n0 + m)*(16*NT);
        #pragma unroll
        for (int nt = 0; nt < NT; ++nt)
          op[nt*16 + r] = acc[mt][nt][rr];
      }
    }
}

// ---------------------------------------------------------------------------
// k_epi: v = sum_{s<8} partial[s] + bc + bd (+resid);
// outRaw (f32, optional), outRelu (fp16, optional)
// ---------------------------------------------------------------------------
__global__ __launch_bounds__(256)
void k_epi(const float* __restrict__ partial, const float* __restrict__ bc,
           const float* __restrict__ bd, const float* __restrict__ resid,
           float* __restrict__ outRaw, unsigned short* __restrict__ outRelu, int total)
{
  const int i = blockIdx.x*256 + threadIdx.x;
  if (i >= total) return;
  float v = 0.f;
  #pragma unroll
  for (int s = 0; s < 8; ++s) v += partial[(size_t)s*total + i];
  const int o = i & 63;
  v += bc[o] + bd[o];
  if (resid)   v += resid[i];
  if (outRaw)  outRaw[i]  = v;
  if (outRelu) outRelu[i] = f2h(fmaxf(v, 0.f));
}

// ---------------------------------------------------------------------------
// k_epi0: layer-0 epilogue — sum 4 segs (bias folded into GEMM), relu, fp16.
// ---------------------------------------------------------------------------
__global__ __launch_bounds__(256)
void k_epi0(const float* __restrict__ partial, unsigned short* __restrict__ outRelu,
            int total)
{
  const int i = blockIdx.x*256 + threadIdx.x;
  if (i >= total) return;
  float v = 0.f;
  #pragma unroll
  for (int s = 0; s < 4; ++s) v += partial[(size_t)s*total + i];
  outRelu[i] = f2h(fmaxf(v, 0.f));
}

// ---------------------------------------------------------------------------
extern "C" void kernel_launch(void* const* d_in, const int* in_sizes, int n_in,
                              void* d_out, int out_size, void* d_ws, size_t ws_size,
                              hipStream_t stream)
{
  const float* pos  = (const float*)d_in[0];
  const float* vel  = (const float*)d_in[1];
  const float* box  = (const float*)d_in[2];
  const float* boxf = (const float*)d_in[3];
  const float* Wc0f = (const float*)d_in[4];
  const float* bc0f = (const float*)d_in[5];
  const float* Wc0o = (const float*)d_in[6];
  const float* bc0o = (const float*)d_in[7];
  const float* Wd0  = (const float*)d_in[8];
  const float* bd0  = (const float*)d_in[9];
  const float* Wc1  = (const float*)d_in[10];
  const float* bc1  = (const float*)d_in[11];
  const float* Wd1  = (const float*)d_in[12];
  const float* bd1  = (const float*)d_in[13];
  const float* Wc2  = (const float*)d_in[14];
  const float* bc2  = (const float*)d_in[15];
  const float* Wd2  = (const float*)d_in[16];
  const float* bd2  = (const float*)d_in[17];
  const int* nfi = (const int*)d_in[18];
  const int* nbi = (const int*)d_in[20];
  const int NF = in_sizes[0]/3;
  const int KB = in_sizes[20]/NF;
  float* out = (float*)d_out;

  const int Kp1 = 6528, Kp2 = 4416;        // padded-bin K extents (%64==0)

  char* wsb = (char*)d_ws;
  auto alloc = [&](size_t bytes){ char* p = wsb; wsb += (bytes + 255) & ~(size_t)255; return p; };
  unsigned short* inp1 = (unsigned short*)alloc((size_t)NF*96*2);
  float* ans1    = (float*)alloc((size_t)NF*64*4);
  unsigned short* inp2 = (unsigned short*)alloc((size_t)NF*64*2);
  float* partial = (float*)alloc((size_t)8*NF*64*4);   // also holds 4*NF*96 (layer 0)
  unsigned short* Bpk1 = (unsigned short*)alloc((size_t)64*Kp1*2);
  unsigned short* Bpk2 = (unsigned short*)alloc((size_t)64*Kp2*2);
  unsigned short* Bpk0 = (unsigned short*)alloc((size_t)96*512*2);
  unsigned short* Abuf = (unsigned short*)wsb;
  size_t usedB = (size_t)(wsb - (char*)d_ws);
  size_t availUS = (ws_size > usedB) ? (ws_size - usedB)/2 : 0;

  auto chunkOf = [&](int Kpad)->int{
    long long c = (long long)(availUS / (size_t)Kpad);
    if (c >= NF) return NF;
    int ch = (int)c & ~127;
    if (ch < 128) ch = 128;
    return ch;
  };

  // prepack B matrices (fp16, transposed + chunk-swizzled, zero at bin pads)
  k_bpack0<<<(96*64 + 255)/256, 256, 0, stream>>>(Wc0f, Wc0o, Wd0, bc0o, bc0f, bd0, Bpk0);
  k_bpack<<<(64*(Kp1/8) + 255)/256, 256, 0, stream>>>(Wc1, Wd1, 96, 100, 96, Kp1, Bpk1);
  k_bpack<<<(64*(Kp2/8) + 255)/256, 256, 0, stream>>>(Wc2, Wd2, 64,  68, 64, Kp2, Bpk2);

  // layer 0
  {
    k0_scatter<<<NF, 256, 0, stream>>>(pos, vel, box, boxf, nfi, nbi, KB, Abuf);
    int tiles = (NF + 127)/128;
    k2_gemm<6><<<dim3(tiles, 4), 256, 0, stream>>>(Abuf, Bpk0, partial, 0, NF,
                                                   512, 8, 2, NF);
    k_epi0<<<(NF*96 + 255)/256, 256, 0, stream>>>(partial, inp1, NF*96);
  }
  // layer 1: conv1 + dense1 (K-extension)
  {
    int CH = chunkOf(Kp1);
    for (int n0 = 0; n0 < NF; n0 += CH){
      int CHa = (n0 + CH < NF) ? CH : (NF - n0);
      k1_scatter<96><<<CHa, 256, 0, stream>>>(pos, inp1, nfi, n0, Abuf);
      int tiles = (CHa + 127)/128;
      k2_gemm<4><<<dim3(tiles, 8), 256, 0, stream>>>(Abuf, Bpk1, partial, n0, CHa,
                                                     Kp1, Kp1/64, 13, NF);
    }
    k_epi<<<(NF*64 + 255)/256, 256, 0, stream>>>(partial, bc1, bd1, nullptr,
                                                 ans1, inp2, NF*64);
  }
  // layer 2: conv2 + dense2 + residual
  {
    int CH = chunkOf(Kp2);
    for (int n0 = 0; n0 < NF; n0 += CH){
      int CHa = (n0 + CH < NF) ? CH : (NF - n0);
      k1_scatter<64><<<CHa, 256, 0, stream>>>(pos, inp2, nfi, n0, Abuf);
      int tiles = (CHa + 127)/128;
      k2_gemm<4><<<dim3(tiles, 8), 256, 0, stream>>>(Abuf, Bpk2, partial, n0, CHa,
                                                     Kp2, Kp2/64, 9, NF);
    }
    k_epi<<<(NF*64 + 255)/256, 256, 0, stream>>>(partial, bc2, bd2, ans1,
                                                 out, nullptr, NF*64);
  }
}